// Round 5
// baseline (200.832 us; speedup 1.0000x reference)
//
#include <hip/hip_runtime.h>
#include <math.h>

#define B_CONST 256
#define V_CONST 128000           // 32000 float4 per row
#define L_CONST 200
#define SLICES  25               // counting tasks per row
#define F4_PER_SLICE 1280        // 32000 / 25
#define F4_PER_LANE  20          // 1280 / 64

typedef float f32x4 __attribute__((ext_vector_type(4)));

// ws layout: int partial[SLICES*B], int sub[B], int dist[B]

// grid (13, 256), block 128 (= 2 waves). Global wave id within row:
// t = blockIdx.x*2 + (tid>>6), t in 0..25. t<25: counting slice t; t==25: history.
// ZERO barriers, ZERO LDS: each wave is an independent task; counts accumulate
// on the scalar pipe via ballot+popcount.
// NOTE: loads are PLAIN (cached) this round — isolating the nontemporal-load
// variable vs the verified 195.88 µs baseline. m13's 6.29 TB/s ceiling was
// measured with cached loads; nt no-allocate may be throttling the read stream.
__global__ __launch_bounds__(128, 4) void rank_count_kernel(
    const float* __restrict__ scores,
    const int* __restrict__ labels,
    const int* __restrict__ seqs,
    int* __restrict__ partial,
    int* __restrict__ sub,
    int* __restrict__ dist)
{
    const int lane = threadIdx.x & 63;
    const int b    = blockIdx.y;
    const int t    = blockIdx.x * 2 + (threadIdx.x >> 6);

    const float* row = scores + (size_t)b * V_CONST;

    // uniform scalar chain: labels[b] -> row[label]; issued first so its
    // latency hides under the vector loads below.
    const float predict = row[labels[b]];

    if (t < SLICES) {
        // ---- streaming count wave: 20 KB contiguous, all 20 loads in flight
        const f32x4* row4 = (const f32x4*)row;
        const int base = t * F4_PER_SLICE + lane;
        f32x4 v[F4_PER_LANE];
        #pragma unroll
        for (int k = 0; k < F4_PER_LANE; ++k)
            v[k] = row4[base + k * 64];

        // ballot+popcount: v_cmp (VALU) + s_bcnt1/s_add (scalar pipe, co-issued);
        // cnt is wave-uniform, no cross-lane shuffle reduce needed.
        int cnt = 0;
        #pragma unroll
        for (int k = 0; k < F4_PER_LANE; ++k) {
            cnt += __popcll(__ballot(v[k][0] > predict));
            cnt += __popcll(__ballot(v[k][1] > predict));
            cnt += __popcll(__ballot(v[k][2] > predict));
            cnt += __popcll(__ballot(v[k][3] > predict));
        }
        if (lane == 0) partial[t * B_CONST + b] = cnt;
    } else {
        // ---- history wave: dedup 200 entries in-register via shfl broadcast
        const int* sq = seqs + b * L_CONST;
        int e[4], val[4];
        float sv[4];
        #pragma unroll
        for (int k = 0; k < 4; ++k) {
            e[k]   = lane + 64 * k;
            val[k] = (e[k] < L_CONST) ? sq[e[k]] : -1;          // -1 sentinel
            sv[k]  = (e[k] < L_CONST) ? row[val[k]] : -1.0e30f; // gather early
        }
        bool first[4] = {true, true, true, true};
        #pragma unroll
        for (int jb = 0; jb < 4; ++jb) {
            for (int l = 0; l < 64; ++l) {
                const int j  = jb * 64 + l;
                const int sj = __shfl(val[jb], l);
                #pragma unroll
                for (int k = jb; k < 4; ++k)   // j < e[k] impossible for k < jb
                    if (j < e[k] && sj == val[k]) first[k] = false;
            }
        }
        int d = 0, s = 0;
        #pragma unroll
        for (int k = 0; k < 4; ++k) {
            const bool isdist = first[k] && (e[k] < L_CONST);
            d += __popcll(__ballot(isdist));
            s += __popcll(__ballot(isdist && (sv[k] > predict)));
        }
        if (lane == 0) { dist[b] = d; sub[b] = s; }
    }
}

// single wave, 64 threads, 4 rows per lane, zero barriers
__global__ __launch_bounds__(64) void finalize_kernel(
    const int* __restrict__ partial,
    const int* __restrict__ sub,
    const int* __restrict__ dist,
    float* __restrict__ out)
{
    const int l = threadIdx.x;               // 0..63

    float acc[12];
    #pragma unroll
    for (int q = 0; q < 12; ++q) acc[q] = 0.0f;

    const float ks[5] = {1.0f, 5.0f, 10.0f, 20.0f, 50.0f};

    #pragma unroll
    for (int r = 0; r < 4; ++r) {
        const int b = l + 64 * r;            // coalesced within the wave
        int gt = 0;
        #pragma unroll
        for (int s = 0; s < SLICES; ++s) gt += partial[s * B_CONST + b];
        const float rank  = (float)(gt - sub[b]);
        const float valid = (float)(V_CONST - dist[b]);

        const float invlog = 1.0f / log2f(rank + 2.0f);
        #pragma unroll
        for (int i = 0; i < 5; ++i) {
            const float ind = (rank < ks[i]) ? 1.0f : 0.0f;
            acc[2 * i]     += ind * invlog;  // NDCG@k
            acc[2 * i + 1] += ind;           // Recall@k
        }
        acc[10] += 1.0f / (rank + 1.0f);     // MRR
        acc[11] += 1.0f - rank / valid;      // AUC-like
    }

    #pragma unroll
    for (int q = 0; q < 12; ++q) {
        float v = acc[q];
        #pragma unroll
        for (int off = 32; off > 0; off >>= 1)
            v += __shfl_down(v, off, 64);
        if (l == 0) out[q] = v * (1.0f / B_CONST);
    }
    if (l == 0) out[12] = 0.0f;
}

extern "C" void kernel_launch(void* const* d_in, const int* in_sizes, int n_in,
                              void* d_out, int out_size, void* d_ws, size_t ws_size,
                              hipStream_t stream) {
    const float* scores = (const float*)d_in[0];
    const int*   labels = (const int*)d_in[1];
    const int*   seqs   = (const int*)d_in[2];
    float* out = (float*)d_out;
    int*   ws  = (int*)d_ws;

    int* partial = ws;                               // SLICES*B
    int* sub     = ws + SLICES * B_CONST;            // B
    int* dist    = ws + SLICES * B_CONST + B_CONST;  // B

    rank_count_kernel<<<dim3(13, B_CONST), 128, 0, stream>>>(
        scores, labels, seqs, partial, sub, dist);
    finalize_kernel<<<1, 64, 0, stream>>>(partial, sub, dist, out);
}

// Round 6
// 196.166 us; speedup vs baseline: 1.0238x; 1.0238x over previous
//
#include <hip/hip_runtime.h>
#include <math.h>

#define B_CONST 256
#define V_CONST 128000           // 32000 float4 per row
#define L_CONST 200
#define SLICES  25               // counting tasks per row
#define F4_PER_SLICE 1280        // 32000 / 25
#define F4_PER_LANE  20          // 1280 / 64

typedef float f32x4 __attribute__((ext_vector_type(4)));

// ws layout: int partial[SLICES*B], int sub[B], int dist[B]
//
// VERIFIED BEST (195.88 µs, round 2; A/B round 5 showed NT loads are worth
// -4.9 µs vs plain cached loads in this exact structure).
//
// grid (13, 256), block 128 (= 2 waves). Global wave id within row:
// t = blockIdx.x*2 + (tid>>6), t in 0..25. t<25: counting slice t; t==25: history.
// ZERO barriers, ZERO LDS: each wave is an independent task; counts accumulate
// on the scalar pipe via ballot+popcount. Many short waves (26/CU) win over
// fewer deep-pipelined waves (round-4 regression: +3.7 µs).
__global__ __launch_bounds__(128, 4) void rank_count_kernel(
    const float* __restrict__ scores,
    const int* __restrict__ labels,
    const int* __restrict__ seqs,
    int* __restrict__ partial,
    int* __restrict__ sub,
    int* __restrict__ dist)
{
    const int lane = threadIdx.x & 63;
    const int b    = blockIdx.y;
    const int t    = blockIdx.x * 2 + (threadIdx.x >> 6);

    const float* row = scores + (size_t)b * V_CONST;

    // uniform scalar chain (s_load): labels[b] -> row[label]; issued first so
    // its latency hides under the vector loads below.
    const float predict = row[labels[b]];

    if (t < SLICES) {
        // ---- streaming count wave: 20 KB contiguous, all 20 loads in flight.
        // Non-temporal: scores is read-once; nt skips L2 allocation and avoids
        // colliding with the poison-fill's dirty lines (A/B: -4.9 µs).
        const f32x4* row4 = (const f32x4*)row;
        const int base = t * F4_PER_SLICE + lane;
        f32x4 v[F4_PER_LANE];
        #pragma unroll
        for (int k = 0; k < F4_PER_LANE; ++k)
            v[k] = __builtin_nontemporal_load(row4 + base + k * 64);

        // ballot+popcount: v_cmp (VALU) + s_bcnt1/s_add (scalar pipe, co-issued);
        // cnt is wave-uniform, no cross-lane shuffle reduce needed.
        int cnt = 0;
        #pragma unroll
        for (int k = 0; k < F4_PER_LANE; ++k) {
            cnt += __popcll(__ballot(v[k][0] > predict));
            cnt += __popcll(__ballot(v[k][1] > predict));
            cnt += __popcll(__ballot(v[k][2] > predict));
            cnt += __popcll(__ballot(v[k][3] > predict));
        }
        if (lane == 0) partial[t * B_CONST + b] = cnt;
    } else {
        // ---- history wave: dedup 200 entries in-register via shfl broadcast
        const int* sq = seqs + b * L_CONST;
        int e[4], val[4];
        float sv[4];
        #pragma unroll
        for (int k = 0; k < 4; ++k) {
            e[k]   = lane + 64 * k;
            val[k] = (e[k] < L_CONST) ? sq[e[k]] : -1;          // -1 sentinel
            sv[k]  = (e[k] < L_CONST) ? row[val[k]] : -1.0e30f; // gather early
        }
        bool first[4] = {true, true, true, true};
        #pragma unroll
        for (int jb = 0; jb < 4; ++jb) {
            for (int l = 0; l < 64; ++l) {
                const int j  = jb * 64 + l;
                const int sj = __shfl(val[jb], l);
                #pragma unroll
                for (int k = jb; k < 4; ++k)   // j < e[k] impossible for k < jb
                    if (j < e[k] && sj == val[k]) first[k] = false;
            }
        }
        int d = 0, s = 0;
        #pragma unroll
        for (int k = 0; k < 4; ++k) {
            const bool isdist = first[k] && (e[k] < L_CONST);
            d += __popcll(__ballot(isdist));
            s += __popcll(__ballot(isdist && (sv[k] > predict)));
        }
        if (lane == 0) { dist[b] = d; sub[b] = s; }
    }
}

// single wave, 64 threads, 4 rows per lane, zero barriers
__global__ __launch_bounds__(64) void finalize_kernel(
    const int* __restrict__ partial,
    const int* __restrict__ sub,
    const int* __restrict__ dist,
    float* __restrict__ out)
{
    const int l = threadIdx.x;               // 0..63

    float acc[12];
    #pragma unroll
    for (int q = 0; q < 12; ++q) acc[q] = 0.0f;

    const float ks[5] = {1.0f, 5.0f, 10.0f, 20.0f, 50.0f};

    #pragma unroll
    for (int r = 0; r < 4; ++r) {
        const int b = l + 64 * r;            // coalesced within the wave
        int gt = 0;
        #pragma unroll
        for (int s = 0; s < SLICES; ++s) gt += partial[s * B_CONST + b];
        const float rank  = (float)(gt - sub[b]);
        const float valid = (float)(V_CONST - dist[b]);

        const float invlog = 1.0f / log2f(rank + 2.0f);
        #pragma unroll
        for (int i = 0; i < 5; ++i) {
            const float ind = (rank < ks[i]) ? 1.0f : 0.0f;
            acc[2 * i]     += ind * invlog;  // NDCG@k
            acc[2 * i + 1] += ind;           // Recall@k
        }
        acc[10] += 1.0f / (rank + 1.0f);     // MRR
        acc[11] += 1.0f - rank / valid;      // AUC-like
    }

    #pragma unroll
    for (int q = 0; q < 12; ++q) {
        float v = acc[q];
        #pragma unroll
        for (int off = 32; off > 0; off >>= 1)
            v += __shfl_down(v, off, 64);
        if (l == 0) out[q] = v * (1.0f / B_CONST);
    }
    if (l == 0) out[12] = 0.0f;
}

extern "C" void kernel_launch(void* const* d_in, const int* in_sizes, int n_in,
                              void* d_out, int out_size, void* d_ws, size_t ws_size,
                              hipStream_t stream) {
    const float* scores = (const float*)d_in[0];
    const int*   labels = (const int*)d_in[1];
    const int*   seqs   = (const int*)d_in[2];
    float* out = (float*)d_out;
    int*   ws  = (int*)d_ws;

    int* partial = ws;                               // SLICES*B
    int* sub     = ws + SLICES * B_CONST;            // B
    int* dist    = ws + SLICES * B_CONST + B_CONST;  // B

    rank_count_kernel<<<dim3(13, B_CONST), 128, 0, stream>>>(
        scores, labels, seqs, partial, sub, dist);
    finalize_kernel<<<1, 64, 0, stream>>>(partial, sub, dist, out);
}